// Round 8
// baseline (226.297 us; speedup 1.0000x reference)
//
#include <hip/hip_runtime.h>
#include <math.h>

#define BB 4
#define HH 8
#define NN 2048
#define DD 64
#define KTOP 16
#define CUT_MARGIN 1e-3f

typedef _Float16 half_t;
typedef __attribute__((ext_vector_type(8))) _Float16 half8;
typedef __attribute__((ext_vector_type(4))) float floatx4;

// async 16B global->LDS copy (hardware scatters lane i at ldsbase + i*16)
__device__ __forceinline__ void gl_lds16(const half_t* g, half_t* l) {
    __builtin_amdgcn_global_load_lds(
        (const __attribute__((address_space(1))) void*)g,
        (__attribute__((address_space(3))) void*)l, 16, 0, 0);
}

// ---------------------------------------------------------------------------
// Kernel 0: split fp32 q,k into f16 hi + f16 (lo*2^11), stored PRE-SWIZZLED.
// (unchanged from R5-R7, passed)
// ---------------------------------------------------------------------------
__global__ __launch_bounds__(256) void split_swz(const float* __restrict__ q,
                                                 const float* __restrict__ kk,
                                                 half_t* __restrict__ qhi,
                                                 half_t* __restrict__ qlo,
                                                 half_t* __restrict__ khi,
                                                 half_t* __restrict__ klo) {
    const int uidx = blockIdx.x * 256 + threadIdx.x;  // 16B-unit index
    const int row  = uidx >> 3;
    const int kg   = uidx & 7;
    const size_t src = (size_t)uidx * 8;
    const size_t dst = (size_t)row * 64 + (size_t)((kg ^ (row & 7)) << 3);

    float a[8], b[8];
    *(float4*)&a[0] = *(const float4*)(q + src);
    *(float4*)&a[4] = *(const float4*)(q + src + 4);
    *(float4*)&b[0] = *(const float4*)(kk + src);
    *(float4*)&b[4] = *(const float4*)(kk + src + 4);
    half8 qh, ql, kh, kl;
#pragma unroll
    for (int e = 0; e < 8; ++e) {
        half_t hq = (half_t)a[e];
        half_t hk = (half_t)b[e];
        qh[e] = hq; ql[e] = (half_t)((a[e] - (float)hq) * 2048.0f);
        kh[e] = hk; kl[e] = (half_t)((b[e] - (float)hk) * 2048.0f);
    }
    *(half8*)(qhi + dst) = qh;
    *(half8*)(qlo + dst) = ql;
    *(half8*)(khi + dst) = kh;
    *(half8*)(klo + dst) = kl;
}

// ---------------------------------------------------------------------------
// Kernel 1: L = (1/64) * sum_{h,d} q.k via f16x3 MFMA (16x16x32_f16).
// (unchanged from R5-R7, passed)
// ---------------------------------------------------------------------------
__global__ __launch_bounds__(256, 2) void gemm_f16x3(const half_t* __restrict__ qhi,
                                                     const half_t* __restrict__ qlo,
                                                     const half_t* __restrict__ khi,
                                                     const half_t* __restrict__ klo,
                                                     float* __restrict__ L) {
    const int b  = blockIdx.z;
    const int i0 = blockIdx.y * 128;
    const int j0 = blockIdx.x * 128;
    const int tid  = threadIdx.x;
    const int wave = __builtin_amdgcn_readfirstlane(tid >> 6);
    const int lane = tid & 63;
    const int wr = wave >> 1, wc = wave & 1;
    const int lm = lane & 15, quad = lane >> 4;

    __shared__ __align__(16) half_t Ah[128 * 64];
    __shared__ __align__(16) half_t Al[128 * 64];
    __shared__ __align__(16) half_t Bh[128 * 64];
    __shared__ __align__(16) half_t Bl[128 * 64];

    const int off0 = (lane >> 3) * 64 + (lane & 7) * 8;

    floatx4 acc1[4][4], acc2[4][4];
#pragma unroll
    for (int tr = 0; tr < 4; ++tr)
#pragma unroll
        for (int tc = 0; tc < 4; ++tc) {
            acc1[tr][tc] = (floatx4)0.0f;
            acc2[tr][tc] = (floatx4)0.0f;
        }

    for (int h = 0; h < HH; ++h) {
        const size_t aoff = ((size_t)(b * HH + h) * NN + i0) * DD;
        const size_t boff = ((size_t)(b * HH + h) * NN + j0) * DD;
        const half_t* gbase;
        half_t* lbase;
        if      (wave == 0) { gbase = qhi + aoff; lbase = Ah; }
        else if (wave == 1) { gbase = qlo + aoff; lbase = Al; }
        else if (wave == 2) { gbase = khi + boff; lbase = Bh; }
        else                { gbase = klo + boff; lbase = Bl; }
        gbase += off0;

        __syncthreads();
#pragma unroll
        for (int i = 0; i < 16; ++i)
            gl_lds16(gbase + i * 512, lbase + i * 512);
        __syncthreads();

#pragma unroll
        for (int ks = 0; ks < 2; ++ks) {
            half8 ah[4], al[4], bh[4], bl[4];
            const int unit = ks * 4 + quad;
#pragma unroll
            for (int t = 0; t < 4; ++t) {
                const int am = wr * 64 + t * 16 + lm;
                const int bm = wc * 64 + t * 16 + lm;
                const int ai = am * 64 + ((unit ^ (am & 7)) << 3);
                const int bi = bm * 64 + ((unit ^ (bm & 7)) << 3);
                ah[t] = *(const half8*)&Ah[ai];
                al[t] = *(const half8*)&Al[ai];
                bh[t] = *(const half8*)&Bh[bi];
                bl[t] = *(const half8*)&Bl[bi];
            }
#pragma unroll
            for (int tr = 0; tr < 4; ++tr)
#pragma unroll
                for (int tc = 0; tc < 4; ++tc) {
                    acc1[tr][tc] = __builtin_amdgcn_mfma_f32_16x16x32_f16(
                        ah[tr], bh[tc], acc1[tr][tc], 0, 0, 0);
                    acc2[tr][tc] = __builtin_amdgcn_mfma_f32_16x16x32_f16(
                        ah[tr], bl[tc], acc2[tr][tc], 0, 0, 0);
                    acc2[tr][tc] = __builtin_amdgcn_mfma_f32_16x16x32_f16(
                        al[tr], bh[tc], acc2[tr][tc], 0, 0, 0);
                }
        }
    }

    const float s1 = 0.015625f;
    const float s2 = 0.015625f / 2048.0f;
#pragma unroll
    for (int tr = 0; tr < 4; ++tr)
#pragma unroll
        for (int r = 0; r < 4; ++r) {
            const int grow = i0 + wr * 64 + tr * 16 + quad * 4 + r;
            float* Lp = L + ((size_t)b * NN + grow) * NN + j0 + wc * 64 + lm;
#pragma unroll
            for (int tc = 0; tc < 4; ++tc)
                Lp[tc * 16] = acc1[tr][tc][r] * s1 + acc2[tr][tc][r] * s2;
        }
}

// ---------------------------------------------------------------------------
// Kernel 2 (v5): 256-thread blocks, 4 independent waves = 4 rows, ZERO
// barriers (per-wave LDS slices, same-wave ordering). Phase D's serial
// min-retire loop replaced by one fixed 64-wide bitonic sort of the u64
// keys (pads=+max sort to top; candidates ascending in lanes 0..c-1;
// threshold = lane c-16 -- identical order statistic to the retire loop).
// Decision semantics otherwise identical to R6/R7 (passed).
// ---------------------------------------------------------------------------
__device__ __forceinline__ unsigned long long flip64(double x) {
    unsigned long long v = (unsigned long long)__double_as_longlong(x);
    return v ^ ((0ULL - (v >> 63)) | 0x8000000000000000ULL);
}
__device__ __forceinline__ double unflip64(unsigned long long k) {
    unsigned long long v = (k >> 63) ? (k ^ 0x8000000000000000ULL) : ~k;
    return __longlong_as_double((long long)v);
}

__global__ __launch_bounds__(256) void topk_mask(float* __restrict__ LM,
                                                 const float* __restrict__ u) {
    const int wave = threadIdx.x >> 6, lane = threadIdx.x & 63;
    const int row = blockIdx.x * 4 + wave;
    float* lrow = LM + (size_t)row * NN;
    const float* urow = u + (size_t)row * NN;

    __shared__ int s_idx[4][64];

    // ---- phase A: stream row, keep only z + hard bitmask ----
    float z[32];
    unsigned hard = 0;
    float4 lb = *(const float4*)(lrow + lane * 4);
    float4 ub = *(const float4*)(urow + lane * 4);
#pragma unroll
    for (int e = 0; e < 8; ++e) {
        float4 lnx, unx;
        if (e < 7) {
            lnx = *(const float4*)(lrow + (e + 1) * 256 + lane * 4);
            unx = *(const float4*)(urow + (e + 1) * 256 + lane * 4);
        }
        const float* ls = (const float*)&lb;
        const float* us = (const float*)&ub;
#pragma unroll
        for (int s = 0; s < 4; ++s) {
            float w = -__logf(us[s] + 1e-9f);
            z[e * 4 + s] = ls[s] - __logf(w + 1e-9f);
            hard |= (us[s] > 0.999f ? 1u : 0u) << (e * 4 + s);
        }
        lb = lnx; ub = unx;
    }

    // ---- phase B: cutoff = (16th largest of 64 lane-maxima) - margin ----
    float v = z[0];
#pragma unroll
    for (int r = 1; r < 32; ++r) v = fmaxf(v, z[r]);
#pragma unroll
    for (int kS = 2; kS <= 64; kS <<= 1) {
#pragma unroll
        for (int j = kS >> 1; j > 0; j >>= 1) {
            float o = __shfl_xor(v, j, 64);
            bool asc = ((lane & kS) == 0);
            bool lower = ((lane & j) == 0);
            float mn = fminf(v, o), mx = fmaxf(v, o);
            v = (asc == lower) ? mn : mx;
        }
    }
    const float cut = __shfl(v, 48, 64) - CUT_MARGIN;

    // ---- phase C: ballot-prefix candidate gather (indices only) ----
    int c = 0;
#pragma unroll
    for (int r = 0; r < 32; ++r) {
        bool p = (z[r] >= cut);
        unsigned long long m = __ballot(p);
        if (p) {
            int slot = c + __popcll(m & ((1ULL << lane) - 1ULL));
            if (slot < 64) s_idx[wave][slot] = (r >> 2) * 256 + lane * 4 + (r & 3);
        }
        c += __popcll(m);
    }
    if (c > 64) c = 64;

    // ---- phase D: f64 keys for candidates; 64-wide bitonic sort (fixed
    //      depth); threshold = ascending-sorted lane c-16 ----
    unsigned long long key = 0xFFFFFFFFFFFFFFFFULL;
    if (lane < c) {
        int idx = s_idx[wave][lane];
        double uu = (double)urow[idx] + 1e-9;   // cache-hot gather
        double w  = -log(uu);
        double g  = -log(w + 1e-9);
        key = flip64((double)lrow[idx] + g);
    }
#pragma unroll
    for (int kS = 2; kS <= 64; kS <<= 1) {
#pragma unroll
        for (int j = kS >> 1; j > 0; j >>= 1) {
            unsigned long long o = __shfl_xor(key, j, 64);
            bool asc = ((lane & kS) == 0);
            bool lower = ((lane & j) == 0);
            unsigned long long mn = (key < o) ? key : o;
            unsigned long long mx = (key < o) ? o : key;
            key = (asc == lower) ? mn : mx;
        }
    }
    const double thresh = unflip64(__shfl(key, c - KTOP, 64));

    // ---- phase E: single masked store pass ----
    const float t_hi = (float)thresh + 3e-4f;
    const float t_lo = (float)thresh - 3e-4f;
#pragma unroll
    for (int e = 0; e < 8; ++e) {
        float o[4];
#pragma unroll
        for (int s = 0; s < 4; ++s) {
            const int t = e * 4 + s;
            const float zz = z[t];
            const bool hardb = (hard >> t) & 1u;
            float val;
            if (!hardb && zz > t_hi)      val = 1.0f;
            else if (!hardb && zz < t_lo) val = 0.0f;
            else {   // rare: reload (cache-hot; own element not yet stored)
                const int idx = e * 256 + lane * 4 + s;
                double uu = (double)urow[idx] + 1e-9;
                double w  = -log(uu);
                double g  = -log(w + 1e-9);
                double z64 = (double)lrow[idx] + g;
                val = (z64 >= thresh) ? 1.0f : 0.0f;
            }
            o[s] = val;
        }
        *(float4*)(lrow + e * 256 + lane * 4) = *(float4*)o;
    }
}

extern "C" void kernel_launch(void* const* d_in, const int* in_sizes, int n_in,
                              void* d_out, int out_size, void* d_ws, size_t ws_size,
                              hipStream_t stream) {
    const float* q = (const float*)d_in[0];
    const float* k = (const float*)d_in[1];
    const float* u = (const float*)d_in[2];
    float* out = (float*)d_out;          // logits scratch, then final mask
    const size_t NQ = (size_t)BB * HH * NN * DD;   // 4M elements
    half_t* qhi = (half_t*)d_ws;
    half_t* qlo = qhi + NQ;
    half_t* khi = qlo + NQ;
    half_t* klo = khi + NQ;              // 32 MB total in d_ws

    split_swz<<<(int)(NQ / 8 / 256), 256, 0, stream>>>(q, k, qhi, qlo, khi, klo);

    dim3 grid1(NN / 128, NN / 128, BB);
    gemm_f16x3<<<grid1, 256, 0, stream>>>(qhi, qlo, khi, klo, out);

    topk_mask<<<(BB * NN) / 4, 256, 0, stream>>>(out, u);
}

// Round 9
// 212.824 us; speedup vs baseline: 1.0633x; 1.0633x over previous
//
#include <hip/hip_runtime.h>
#include <math.h>

#define BB 4
#define HH 8
#define NN 2048
#define DD 64
#define KTOP 16
#define CUT_MARGIN 1e-3f

typedef _Float16 half_t;
typedef __attribute__((ext_vector_type(8))) _Float16 half8;
typedef __attribute__((ext_vector_type(4))) float floatx4;

// async 16B global->LDS copy (hardware scatters lane i at ldsbase + i*16)
__device__ __forceinline__ void gl_lds16(const half_t* g, half_t* l) {
    __builtin_amdgcn_global_load_lds(
        (const __attribute__((address_space(1))) void*)g,
        (__attribute__((address_space(3))) void*)l, 16, 0, 0);
}

// ---------------------------------------------------------------------------
// Kernel 0: split fp32 q,k into f16 hi + f16 (lo*2^11), stored PRE-SWIZZLED.
// (unchanged from R5-R8, passed)
// ---------------------------------------------------------------------------
__global__ __launch_bounds__(256) void split_swz(const float* __restrict__ q,
                                                 const float* __restrict__ kk,
                                                 half_t* __restrict__ qhi,
                                                 half_t* __restrict__ qlo,
                                                 half_t* __restrict__ khi,
                                                 half_t* __restrict__ klo) {
    const int uidx = blockIdx.x * 256 + threadIdx.x;  // 16B-unit index
    const int row  = uidx >> 3;
    const int kg   = uidx & 7;
    const size_t src = (size_t)uidx * 8;
    const size_t dst = (size_t)row * 64 + (size_t)((kg ^ (row & 7)) << 3);

    float a[8], b[8];
    *(float4*)&a[0] = *(const float4*)(q + src);
    *(float4*)&a[4] = *(const float4*)(q + src + 4);
    *(float4*)&b[0] = *(const float4*)(kk + src);
    *(float4*)&b[4] = *(const float4*)(kk + src + 4);
    half8 qh, ql, kh, kl;
#pragma unroll
    for (int e = 0; e < 8; ++e) {
        half_t hq = (half_t)a[e];
        half_t hk = (half_t)b[e];
        qh[e] = hq; ql[e] = (half_t)((a[e] - (float)hq) * 2048.0f);
        kh[e] = hk; kl[e] = (half_t)((b[e] - (float)hk) * 2048.0f);
    }
    *(half8*)(qhi + dst) = qh;
    *(half8*)(qlo + dst) = ql;
    *(half8*)(khi + dst) = kh;
    *(half8*)(klo + dst) = kl;
}

// ---------------------------------------------------------------------------
// Kernel 1: L = (1/64) * sum_{h,d} q.k via f16x3 MFMA (16x16x32_f16).
// (unchanged from R5-R8, passed)
// ---------------------------------------------------------------------------
__global__ __launch_bounds__(256, 2) void gemm_f16x3(const half_t* __restrict__ qhi,
                                                     const half_t* __restrict__ qlo,
                                                     const half_t* __restrict__ khi,
                                                     const half_t* __restrict__ klo,
                                                     float* __restrict__ L) {
    const int b  = blockIdx.z;
    const int i0 = blockIdx.y * 128;
    const int j0 = blockIdx.x * 128;
    const int tid  = threadIdx.x;
    const int wave = __builtin_amdgcn_readfirstlane(tid >> 6);
    const int lane = tid & 63;
    const int wr = wave >> 1, wc = wave & 1;
    const int lm = lane & 15, quad = lane >> 4;

    __shared__ __align__(16) half_t Ah[128 * 64];
    __shared__ __align__(16) half_t Al[128 * 64];
    __shared__ __align__(16) half_t Bh[128 * 64];
    __shared__ __align__(16) half_t Bl[128 * 64];

    const int off0 = (lane >> 3) * 64 + (lane & 7) * 8;

    floatx4 acc1[4][4], acc2[4][4];
#pragma unroll
    for (int tr = 0; tr < 4; ++tr)
#pragma unroll
        for (int tc = 0; tc < 4; ++tc) {
            acc1[tr][tc] = (floatx4)0.0f;
            acc2[tr][tc] = (floatx4)0.0f;
        }

    for (int h = 0; h < HH; ++h) {
        const size_t aoff = ((size_t)(b * HH + h) * NN + i0) * DD;
        const size_t boff = ((size_t)(b * HH + h) * NN + j0) * DD;
        const half_t* gbase;
        half_t* lbase;
        if      (wave == 0) { gbase = qhi + aoff; lbase = Ah; }
        else if (wave == 1) { gbase = qlo + aoff; lbase = Al; }
        else if (wave == 2) { gbase = khi + boff; lbase = Bh; }
        else                { gbase = klo + boff; lbase = Bl; }
        gbase += off0;

        __syncthreads();
#pragma unroll
        for (int i = 0; i < 16; ++i)
            gl_lds16(gbase + i * 512, lbase + i * 512);
        __syncthreads();

#pragma unroll
        for (int ks = 0; ks < 2; ++ks) {
            half8 ah[4], al[4], bh[4], bl[4];
            const int unit = ks * 4 + quad;
#pragma unroll
            for (int t = 0; t < 4; ++t) {
                const int am = wr * 64 + t * 16 + lm;
                const int bm = wc * 64 + t * 16 + lm;
                const int ai = am * 64 + ((unit ^ (am & 7)) << 3);
                const int bi = bm * 64 + ((unit ^ (bm & 7)) << 3);
                ah[t] = *(const half8*)&Ah[ai];
                al[t] = *(const half8*)&Al[ai];
                bh[t] = *(const half8*)&Bh[bi];
                bl[t] = *(const half8*)&Bl[bi];
            }
#pragma unroll
            for (int tr = 0; tr < 4; ++tr)
#pragma unroll
                for (int tc = 0; tc < 4; ++tc) {
                    acc1[tr][tc] = __builtin_amdgcn_mfma_f32_16x16x32_f16(
                        ah[tr], bh[tc], acc1[tr][tc], 0, 0, 0);
                    acc2[tr][tc] = __builtin_amdgcn_mfma_f32_16x16x32_f16(
                        ah[tr], bl[tc], acc2[tr][tc], 0, 0, 0);
                    acc2[tr][tc] = __builtin_amdgcn_mfma_f32_16x16x32_f16(
                        al[tr], bh[tc], acc2[tr][tc], 0, 0, 0);
                }
        }
    }

    const float s1 = 0.015625f;
    const float s2 = 0.015625f / 2048.0f;
#pragma unroll
    for (int tr = 0; tr < 4; ++tr)
#pragma unroll
        for (int r = 0; r < 4; ++r) {
            const int grow = i0 + wr * 64 + tr * 16 + quad * 4 + r;
            float* Lp = L + ((size_t)b * NN + grow) * NN + j0 + wc * 64 + lm;
#pragma unroll
            for (int tc = 0; tc < 4; ++tc)
                Lp[tc * 16] = acc1[tr][tc][r] * s1 + acc2[tr][tc][r] * s2;
        }
}

// ---------------------------------------------------------------------------
// Kernel 2 (v6): one wave per row (64-thr blocks, R7's best-measured shape).
// Phase D = fixed-depth 64-wide u64 bitonic (R8 semantics, passed).
// Phase E = band|hard bitmask resolved in ONE cold f64 loop that patches
// z[t] to +-1e30 BEFORE any store (single f64-log instance, ~10KB smaller
// kernel, no load-after-store hazard), then a pure-f32 store loop.
// ---------------------------------------------------------------------------
__device__ __forceinline__ unsigned long long flip64(double x) {
    unsigned long long v = (unsigned long long)__double_as_longlong(x);
    return v ^ ((0ULL - (v >> 63)) | 0x8000000000000000ULL);
}
__device__ __forceinline__ double unflip64(unsigned long long k) {
    unsigned long long v = (k >> 63) ? (k ^ 0x8000000000000000ULL) : ~k;
    return __longlong_as_double((long long)v);
}

__global__ __launch_bounds__(64) void topk_mask(float* __restrict__ LM,
                                                const float* __restrict__ u) {
    const int row  = blockIdx.x;
    const int lane = threadIdx.x;          // 0..63, one wave
    float* lrow = LM + (size_t)row * NN;
    const float* urow = u + (size_t)row * NN;

    __shared__ int s_idx[64];

    // ---- phase A: stream row, keep only z + hard bitmask ----
    float z[32];
    unsigned hard = 0;
    float4 lb = *(const float4*)(lrow + lane * 4);
    float4 ub = *(const float4*)(urow + lane * 4);
#pragma unroll
    for (int e = 0; e < 8; ++e) {
        float4 lnx, unx;
        if (e < 7) {
            lnx = *(const float4*)(lrow + (e + 1) * 256 + lane * 4);
            unx = *(const float4*)(urow + (e + 1) * 256 + lane * 4);
        }
        const float* ls = (const float*)&lb;
        const float* us = (const float*)&ub;
#pragma unroll
        for (int s = 0; s < 4; ++s) {
            float w = -__logf(us[s] + 1e-9f);
            z[e * 4 + s] = ls[s] - __logf(w + 1e-9f);
            hard |= (us[s] > 0.999f ? 1u : 0u) << (e * 4 + s);
        }
        lb = lnx; ub = unx;
    }

    // ---- phase B: cutoff = (16th largest of 64 lane-maxima) - margin ----
    float v = z[0];
#pragma unroll
    for (int r = 1; r < 32; ++r) v = fmaxf(v, z[r]);
#pragma unroll
    for (int kS = 2; kS <= 64; kS <<= 1) {
#pragma unroll
        for (int j = kS >> 1; j > 0; j >>= 1) {
            float o = __shfl_xor(v, j, 64);
            bool asc = ((lane & kS) == 0);
            bool lower = ((lane & j) == 0);
            float mn = fminf(v, o), mx = fmaxf(v, o);
            v = (asc == lower) ? mn : mx;
        }
    }
    const float cut = __shfl(v, 48, 64) - CUT_MARGIN;

    // ---- phase C: ballot-prefix candidate gather (indices only) ----
    int c = 0;
#pragma unroll
    for (int r = 0; r < 32; ++r) {
        bool p = (z[r] >= cut);
        unsigned long long m = __ballot(p);
        if (p) {
            int slot = c + __popcll(m & ((1ULL << lane) - 1ULL));
            if (slot < 64) s_idx[slot] = (r >> 2) * 256 + lane * 4 + (r & 3);
        }
        c += __popcll(m);
    }
    if (c > 64) c = 64;

    // ---- phase D: f64 keys; fixed 64-wide bitonic sort (ascending);
    //      threshold = sorted lane c-16 (exact 16th-largest z64) ----
    unsigned long long key = 0xFFFFFFFFFFFFFFFFULL;
    if (lane < c) {
        int idx = s_idx[lane];
        double uu = (double)urow[idx] + 1e-9;   // cache-hot gather
        double w  = -log(uu);
        double g  = -log(w + 1e-9);
        key = flip64((double)lrow[idx] + g);
    }
#pragma unroll
    for (int kS = 2; kS <= 64; kS <<= 1) {
#pragma unroll
        for (int j = kS >> 1; j > 0; j >>= 1) {
            unsigned long long o = __shfl_xor(key, j, 64);
            bool asc = ((lane & kS) == 0);
            bool lower = ((lane & j) == 0);
            unsigned long long mn = (key < o) ? key : o;
            unsigned long long mx = (key < o) ? o : key;
            key = (asc == lower) ? mn : mx;
        }
    }
    const double thresh = unflip64(__shfl(key, c - KTOP, 64));

    // ---- phase E0: band|hard elements resolved in f64 ONCE, patch z ----
    const float t_hi = (float)thresh + 3e-4f;
    const float t_lo = (float)thresh - 3e-4f;
    unsigned bm = hard;
#pragma unroll
    for (int r = 0; r < 32; ++r)
        bm |= ((z[r] <= t_hi && z[r] >= t_lo) ? 1u : 0u) << r;
    while (bm) {           // expected ~0-2 iterations per wave, sparse exec
        int t = __builtin_ctz(bm);
        bm &= bm - 1;
        const int idx = (t >> 2) * 256 + lane * 4 + (t & 3);
        double uu = (double)urow[idx] + 1e-9;
        double w  = -log(uu);
        double g  = -log(w + 1e-9);
        double z64 = (double)lrow[idx] + g;    // L still intact (no stores yet)
        z[t] = (z64 >= thresh) ? 1.0e30f : -1.0e30f;
    }

    // ---- phase E1: pure-f32 store pass ----
#pragma unroll
    for (int e = 0; e < 8; ++e) {
        float o[4];
#pragma unroll
        for (int s = 0; s < 4; ++s)
            o[s] = (z[e * 4 + s] > t_hi) ? 1.0f : 0.0f;
        *(float4*)(lrow + e * 256 + lane * 4) = *(float4*)o;
    }
}

extern "C" void kernel_launch(void* const* d_in, const int* in_sizes, int n_in,
                              void* d_out, int out_size, void* d_ws, size_t ws_size,
                              hipStream_t stream) {
    const float* q = (const float*)d_in[0];
    const float* k = (const float*)d_in[1];
    const float* u = (const float*)d_in[2];
    float* out = (float*)d_out;          // logits scratch, then final mask
    const size_t NQ = (size_t)BB * HH * NN * DD;   // 4M elements
    half_t* qhi = (half_t*)d_ws;
    half_t* qlo = qhi + NQ;
    half_t* khi = qlo + NQ;
    half_t* klo = khi + NQ;              // 32 MB total in d_ws

    split_swz<<<(int)(NQ / 8 / 256), 256, 0, stream>>>(q, k, qhi, qlo, khi, klo);

    dim3 grid1(NN / 128, NN / 128, BB);
    gemm_f16x3<<<grid1, 256, 0, stream>>>(qhi, qlo, khi, klo, out);

    topk_mask<<<BB * NN, 64, 0, stream>>>(out, u);
}